// Round 1
// baseline (12196.494 us; speedup 1.0000x reference)
//
#include <hip/hip_runtime.h>
#include <stdint.h>

// Persistent cooperative 2-layer LSTM, MI355X.
// - 64 WGs x 256 thr: WGs 0..31 = layer0 (16 h-cols each), 32..63 = layer1.
// - Lag pipeline: iteration it runs L0 step t=it and L1 step t=it-1; one
//   device-wide barrier (monotonic atomic counter in ws) per iteration.
// - Weights converted fp32->bf16 (RNE) once, held in VGPRs for all 1025 steps.
// - h0 passed between steps via a never-reused bf16 ring in ws; h1 via d_out
//   (fp32) and optionally a bf16 ring (if ws is big enough). Producer-side
//   __threadfence() writes XCD L2 back to IC; consumers only ever touch
//   cold lines, so no consumer-side invalidate is needed.

#define SEQ   1024
#define NB    32
#define HID   512
#define NWG   64
#define L0WGS 32

typedef __attribute__((ext_vector_type(8))) short s16x8;
typedef __attribute__((ext_vector_type(4))) float f32x4;

__device__ __forceinline__ uint16_t f2bf(float x) {
    uint32_t u = __float_as_uint(x);
    return (uint16_t)((u + 0x7FFFu + ((u >> 16) & 1u)) >> 16);
}

__device__ __forceinline__ s16x8 pack8(const float* p) {
    float4 a = *(const float4*)p;
    float4 b = *(const float4*)(p + 4);
    s16x8 r;
    r[0] = (short)f2bf(a.x); r[1] = (short)f2bf(a.y);
    r[2] = (short)f2bf(a.z); r[3] = (short)f2bf(a.w);
    r[4] = (short)f2bf(b.x); r[5] = (short)f2bf(b.y);
    r[6] = (short)f2bf(b.z); r[7] = (short)f2bf(b.w);
    return r;
}

__device__ __forceinline__ f32x4 mfma16(s16x8 a, s16x8 b, f32x4 c) {
    return __builtin_amdgcn_mfma_f32_16x16x32_bf16(a, b, c, 0, 0, 0);
}

__device__ __forceinline__ float sigm(float x) { return 1.0f / (1.0f + __expf(-x)); }
__device__ __forceinline__ float tanh_(float x) { return 1.0f - 2.0f / (__expf(2.0f * x) + 1.0f); }

template<bool IS_L0, bool R1>
__device__ void body(const float* __restrict__ xg,
                     const float* __restrict__ Wf, const float* __restrict__ Wi,
                     const float* __restrict__ Wc, const float* __restrict__ Wo,
                     const float* __restrict__ bf_, const float* __restrict__ bi_,
                     const float* __restrict__ bc_, const float* __restrict__ bo_,
                     float* __restrict__ out,
                     uint16_t* __restrict__ ring0, uint16_t* __restrict__ ring1,
                     unsigned* bar, int w)
{
    constexpr int KT  = IS_L0 ? 24 : 32;   // K-tiles of 32 (768 or 1024 deep)
    constexpr int LDW = IS_L0 ? 768 : 1024;

    const int tid  = threadIdx.x;
    const int wave = tid >> 6;             // 0..3 -> gate f,i,c,o
    const int lane = tid & 63;
    const int nloc = lane & 15;            // MFMA col (B n / A m)
    const int quad = lane >> 4;            // 0..3
    const int col0 = w * 16;               // this WG's first h-column

    __shared__ float gbuf[4][NB][16];      // gate preactivations
    __shared__ float cbuf[NB][16];         // cell state (persistent)
    __shared__ float bbuf[4][16];          // biases

    if (tid < 16)       bbuf[0][tid]      = bf_[col0 + tid];
    else if (tid < 32)  bbuf[1][tid - 16] = bi_[col0 + tid - 16];
    else if (tid < 48)  bbuf[2][tid - 32] = bc_[col0 + tid - 32];
    else if (tid < 64)  bbuf[3][tid - 48] = bo_[col0 + tid - 48];
    ((float*)cbuf)[tid] = 0.0f;
    ((float*)cbuf)[tid + 256] = 0.0f;

    // --- Load this wave's B fragments (W^T slice) into registers, bf16 RNE ---
    // B[k][n] = W[col0+nloc][k], fragment layout: n=lane&15, k=quad*8+j.
    const float* Wg = (wave == 0) ? Wf : (wave == 1) ? Wi : (wave == 2) ? Wc : Wo;
    const float* wrow = Wg + (size_t)(col0 + nloc) * LDW + quad * 8;
    s16x8 B[KT];
#pragma unroll
    for (int kt = 0; kt < KT; ++kt) B[kt] = pack8(wrow + kt * 32);

    __syncthreads();

#pragma unroll 1
    for (int it = 0; it <= SEQ; ++it) {
        const bool active = IS_L0 ? (it < SEQ) : (it >= 1);
        if (active) {
            const int t = IS_L0 ? it : it - 1;
            f32x4 acc0 = {0.f, 0.f, 0.f, 0.f};   // batches 0..15
            f32x4 acc1 = {0.f, 0.f, 0.f, 0.f};   // batches 16..31
            if (IS_L0) {
                // x(t) part, fp32 -> bf16 in-register
                const float* px0 = xg + ((size_t)nloc * SEQ + t) * 256 + quad * 8;
                const float* px1 = px0 + (size_t)16 * SEQ * 256;
#pragma unroll
                for (int kt = 0; kt < 8; ++kt) {
                    acc0 = mfma16(pack8(px0 + kt * 32), B[kt], acc0);
                    acc1 = mfma16(pack8(px1 + kt * 32), B[kt], acc1);
                }
                if (it > 0) {  // h0(t-1); zero at t=0 -> skip
                    const uint16_t* ph0 = ring0 + ((size_t)(t - 1) * NB + nloc) * HID + quad * 8;
#pragma unroll
                    for (int kt = 8; kt < 24; ++kt) {
                        s16x8 a0 = *(const s16x8*)(ph0 + (kt - 8) * 32);
                        s16x8 a1 = *(const s16x8*)(ph0 + 16 * HID + (kt - 8) * 32);
                        acc0 = mfma16(a0, B[kt], acc0);
                        acc1 = mfma16(a1, B[kt], acc1);
                    }
                }
            } else {
                // h0(t) part (written by L0 last iteration)
                const uint16_t* ph0 = ring0 + ((size_t)t * NB + nloc) * HID + quad * 8;
#pragma unroll
                for (int kt = 0; kt < 16; ++kt) {
                    s16x8 a0 = *(const s16x8*)(ph0 + kt * 32);
                    s16x8 a1 = *(const s16x8*)(ph0 + 16 * HID + kt * 32);
                    acc0 = mfma16(a0, B[kt], acc0);
                    acc1 = mfma16(a1, B[kt], acc1);
                }
                if (t > 0) {   // h1(t-1); zero at t=0 -> skip
                    if (R1) {
                        const uint16_t* ph1 = ring1 + ((size_t)(t - 1) * NB + nloc) * HID + quad * 8;
#pragma unroll
                        for (int kt = 16; kt < 32; ++kt) {
                            s16x8 a0 = *(const s16x8*)(ph1 + (kt - 16) * 32);
                            s16x8 a1 = *(const s16x8*)(ph1 + 16 * HID + (kt - 16) * 32);
                            acc0 = mfma16(a0, B[kt], acc0);
                            acc1 = mfma16(a1, B[kt], acc1);
                        }
                    } else {
                        const float* po0 = out + ((size_t)nloc * SEQ + (t - 1)) * HID + quad * 8;
                        const float* po1 = po0 + (size_t)16 * SEQ * HID;
#pragma unroll
                        for (int kt = 16; kt < 32; ++kt) {
                            acc0 = mfma16(pack8(po0 + (kt - 16) * 32), B[kt], acc0);
                            acc1 = mfma16(pack8(po1 + (kt - 16) * 32), B[kt], acc1);
                        }
                    }
                }
            }
            // C layout: col=lane&15 (=n), row=quad*4+r (=batch within M-tile)
#pragma unroll
            for (int r = 0; r < 4; ++r) {
                gbuf[wave][quad * 4 + r][nloc]      = acc0[r];
                gbuf[wave][16 + quad * 4 + r][nloc] = acc1[r];
            }
            __syncthreads();
            // elementwise gate fusion: 512 (b,n) items over 256 threads
#pragma unroll
            for (int rep = 0; rep < 2; ++rep) {
                const int item = tid + rep * 256;
                const int b = item >> 4, n = item & 15;
                float pf = gbuf[0][b][n] + bbuf[0][n];
                float pi = gbuf[1][b][n] + bbuf[1][n];
                float pc = gbuf[2][b][n] + bbuf[2][n];
                float pO = gbuf[3][b][n] + bbuf[3][n];
                float f = sigm(pf), i = sigm(pi), g = tanh_(pc), o = sigm(pO);
                float c = f * cbuf[b][n] + i * g;
                cbuf[b][n] = c;
                float h = o * tanh_(c);
                if (IS_L0) {
                    ring0[((size_t)t * NB + b) * HID + col0 + n] = f2bf(h);
                } else {
                    out[((size_t)b * SEQ + t) * HID + col0 + n] = h;
                    if (R1) ring1[((size_t)t * NB + b) * HID + col0 + n] = f2bf(h);
                }
            }
        }
        // ---- device-wide barrier (monotonic counter) ----
        __syncthreads();                       // all waves' stores drained (vmcnt 0)
        if (tid == 0) {
            __threadfence();                   // L2 writeback to IC (agent scope)
            atomicAdd(bar, 1u);
            const unsigned target = (unsigned)(it + 1) * NWG;
            while (__hip_atomic_load(bar, __ATOMIC_RELAXED, __HIP_MEMORY_SCOPE_AGENT) < target)
                __builtin_amdgcn_s_sleep(1);
        }
        __syncthreads();
    }
}

template<bool R1>
__global__ __launch_bounds__(256, 1) void lstm_k(
    const float* __restrict__ x,
    const float* W0f, const float* b0f, const float* W0i, const float* b0i,
    const float* W0c, const float* b0c, const float* W0o, const float* b0o,
    const float* W1f, const float* b1f, const float* W1i, const float* b1i,
    const float* W1c, const float* b1c, const float* W1o, const float* b1o,
    float* out, uint16_t* ring0, uint16_t* ring1, unsigned* bar)
{
    if (blockIdx.x < L0WGS)
        body<true, R1>(x, W0f, W0i, W0c, W0o, b0f, b0i, b0c, b0o,
                       out, ring0, ring1, bar, blockIdx.x);
    else
        body<false, R1>(x, W1f, W1i, W1c, W1o, b1f, b1i, b1c, b1o,
                        out, ring0, ring1, bar, blockIdx.x - L0WGS);
}

extern "C" void kernel_launch(void* const* d_in, const int* in_sizes, int n_in,
                              void* d_out, int out_size, void* d_ws, size_t ws_size,
                              hipStream_t stream) {
    const float* x   = (const float*)d_in[0];
    const float* W0f = (const float*)d_in[1];  const float* b0f = (const float*)d_in[2];
    const float* W0i = (const float*)d_in[3];  const float* b0i = (const float*)d_in[4];
    const float* W0c = (const float*)d_in[5];  const float* b0c = (const float*)d_in[6];
    const float* W0o = (const float*)d_in[7];  const float* b0o = (const float*)d_in[8];
    const float* W1f = (const float*)d_in[9];  const float* b1f = (const float*)d_in[10];
    const float* W1i = (const float*)d_in[11]; const float* b1i = (const float*)d_in[12];
    const float* W1c = (const float*)d_in[13]; const float* b1c = (const float*)d_in[14];
    const float* W1o = (const float*)d_in[15]; const float* b1o = (const float*)d_in[16];
    float* out = (float*)d_out;

    const size_t ring_bytes = (size_t)SEQ * NB * HID * 2;   // 32 MiB
    unsigned*  bar   = (unsigned*)d_ws;
    uint16_t*  ring0 = (uint16_t*)((char*)d_ws + 4096);
    uint16_t*  ring1 = (uint16_t*)((char*)d_ws + 4096 + ring_bytes);
    const bool use_r1 = ws_size >= 4096 + 2 * ring_bytes;

    hipMemsetAsync(d_ws, 0, 4096, stream);   // zero the barrier counter

    if (use_r1)
        hipLaunchKernelGGL(lstm_k<true>, dim3(NWG), dim3(256), 0, stream,
            x, W0f, b0f, W0i, b0i, W0c, b0c, W0o, b0o,
            W1f, b1f, W1i, b1i, W1c, b1c, W1o, b1o, out, ring0, ring1, bar);
    else
        hipLaunchKernelGGL(lstm_k<false>, dim3(NWG), dim3(256), 0, stream,
            x, W0f, b0f, W0i, b0i, W0c, b0c, W0o, b0o,
            W1f, b1f, W1i, b1i, W1c, b1c, W1o, b1o, out, ring0, ring1, bar);
}

// Round 3
// 9451.185 us; speedup vs baseline: 1.2905x; 1.2905x over previous
//
#include <hip/hip_runtime.h>
#include <stdint.h>

// Persistent dataflow 2-layer LSTM, MI355X (gfx950).
// 64 WGs x 256 thr: WGs 0..31 = layer0 (16 h-cols each), 32..63 = layer1.
// No global barrier / threadfence. Cross-WG h-state published with relaxed
// agent-scope (sc0 sc1, cache-bypass) atomic stores into write-once rings,
// signaled by per-step per-WG flags; consumers poll 32 flags with one
// 4B/lane coherent load + __all. L0 and L1 chains are decoupled (L0 runs
// ahead). Weights fp32->bf16 once, held entirely in VGPRs.
// HANG-PROOF: every wait draws from a per-thread global spin budget; on
// exhaustion waits become no-ops (wrong results, but the launch returns).

#define SEQ   1024
#define NB    32
#define HID   512
#define NWG   64
#define L0WGS 32
#define SPIN_BUDGET (1 << 20)

typedef __attribute__((ext_vector_type(8))) short s16x8;
typedef __attribute__((ext_vector_type(4))) float f32x4;

__device__ __forceinline__ uint16_t f2bf(float x) {
    uint32_t u = __float_as_uint(x);
    return (uint16_t)((u + 0x7FFFu + ((u >> 16) & 1u)) >> 16);
}
__device__ __forceinline__ uint32_t pack2bf(float a, float b) {
    return (uint32_t)f2bf(a) | ((uint32_t)f2bf(b) << 16);
}
__device__ __forceinline__ s16x8 pack8(const float* p) {
    float4 a = *(const float4*)p;
    float4 b = *(const float4*)(p + 4);
    s16x8 r;
    r[0] = (short)f2bf(a.x); r[1] = (short)f2bf(a.y);
    r[2] = (short)f2bf(a.z); r[3] = (short)f2bf(a.w);
    r[4] = (short)f2bf(b.x); r[5] = (short)f2bf(b.y);
    r[6] = (short)f2bf(b.z); r[7] = (short)f2bf(b.w);
    return r;
}
__device__ __forceinline__ f32x4 mfma16(s16x8 a, s16x8 b, f32x4 c) {
    return __builtin_amdgcn_mfma_f32_16x16x32_bf16(a, b, c, 0, 0, 0);
}
__device__ __forceinline__ float sigm(float x) { return 1.0f / (1.0f + __expf(-x)); }
__device__ __forceinline__ float tanh_(float x) { return 1.0f - 2.0f / (__expf(2.0f * x) + 1.0f); }

__device__ __forceinline__ void st_u32(uint32_t* p, uint32_t v) {
    __hip_atomic_store(p, v, __ATOMIC_RELAXED, __HIP_MEMORY_SCOPE_AGENT);
}
__device__ __forceinline__ void st_u64(uint64_t* p, uint64_t v) {
    __hip_atomic_store(p, v, __ATOMIC_RELAXED, __HIP_MEMORY_SCOPE_AGENT);
}
__device__ __forceinline__ unsigned ld_flag(const unsigned* p) {
    return __hip_atomic_load(p, __ATOMIC_RELAXED, __HIP_MEMORY_SCOPE_AGENT);
}
// Wait until all 32 flag words at f[0..31] are nonzero, or budget exhausted.
__device__ __forceinline__ void wait32(const unsigned* f, int& budget) {
    const unsigned* p = f + (threadIdx.x & 31);
    for (;;) {
        unsigned v = ld_flag(p);
        if (__all(v != 0)) break;
        if (--budget < 0) break;          // hang-proof: give up, free-run
        __builtin_amdgcn_s_sleep(1);
    }
    asm volatile("" ::: "memory");        // no hoisting of ring loads above poll
}

struct Shared {
    float gbuf[4][NB][16];
    float cbuf[NB][16];
    float bbuf[4][16];
};

__device__ __forceinline__ void load_bias_c(Shared& sh,
        const float* bf_, const float* bi_, const float* bc_, const float* bo_,
        int col0) {
    const int tid = threadIdx.x;
    if (tid < 16)       sh.bbuf[0][tid]      = bf_[col0 + tid];
    else if (tid < 32)  sh.bbuf[1][tid - 16] = bi_[col0 + tid - 16];
    else if (tid < 48)  sh.bbuf[2][tid - 32] = bc_[col0 + tid - 32];
    else if (tid < 64)  sh.bbuf[3][tid - 48] = bo_[col0 + tid - 48];
    ((float2*)sh.cbuf)[tid] = make_float2(0.f, 0.f);
}

__device__ __forceinline__ float2 gates2(Shared& sh, int b, int n) {
    float2 pf = *(float2*)&sh.gbuf[0][b][n];
    float2 pi = *(float2*)&sh.gbuf[1][b][n];
    float2 pc = *(float2*)&sh.gbuf[2][b][n];
    float2 po = *(float2*)&sh.gbuf[3][b][n];
    float2 h;
    {
        float f = sigm(pf.x + sh.bbuf[0][n]);
        float i = sigm(pi.x + sh.bbuf[1][n]);
        float g = tanh_(pc.x + sh.bbuf[2][n]);
        float o = sigm(po.x + sh.bbuf[3][n]);
        float c = f * sh.cbuf[b][n] + i * g;
        sh.cbuf[b][n] = c;
        h.x = o * tanh_(c);
    }
    {
        float f = sigm(pf.y + sh.bbuf[0][n + 1]);
        float i = sigm(pi.y + sh.bbuf[1][n + 1]);
        float g = tanh_(pc.y + sh.bbuf[2][n + 1]);
        float o = sigm(po.y + sh.bbuf[3][n + 1]);
        float c = f * sh.cbuf[b][n + 1] + i * g;
        sh.cbuf[b][n + 1] = c;
        h.y = o * tanh_(c);
    }
    return h;
}

__device__ void body_l0(const float* __restrict__ xg,
                        const float* __restrict__ Wf, const float* __restrict__ Wi,
                        const float* __restrict__ Wc, const float* __restrict__ Wo,
                        const float* __restrict__ bf_, const float* __restrict__ bi_,
                        const float* __restrict__ bc_, const float* __restrict__ bo_,
                        uint16_t* __restrict__ ring0, unsigned* __restrict__ flags0,
                        int w)
{
    const int tid  = threadIdx.x;
    const int wave = tid >> 6;
    const int lane = tid & 63;
    const int nloc = lane & 15;
    const int quad = lane >> 4;
    const int col0 = w * 16;
    int budget = SPIN_BUDGET;

    __shared__ Shared sh;
    load_bias_c(sh, bf_, bi_, bc_, bo_, col0);

    const float* Wg = (wave == 0) ? Wf : (wave == 1) ? Wi : (wave == 2) ? Wc : Wo;
    const float* wrow = Wg + (size_t)(col0 + nloc) * 768 + quad * 8;
    s16x8 B[24];
#pragma unroll
    for (int kt = 0; kt < 24; ++kt) B[kt] = pack8(wrow + kt * 32);

    uint32_t* ring0w = (uint32_t*)ring0;
    __syncthreads();

#pragma unroll 1
    for (int t = 0; t < SEQ; ++t) {
        f32x4 acc0 = {0.f, 0.f, 0.f, 0.f};
        f32x4 acc1 = {0.f, 0.f, 0.f, 0.f};
        // x(t) part first: independent of flags -> overlaps any wait
        {
            const float* px0 = xg + ((size_t)nloc * SEQ + t) * 256 + quad * 8;
            const float* px1 = px0 + (size_t)16 * SEQ * 256;
#pragma unroll
            for (int kt = 0; kt < 8; ++kt) {
                acc0 = mfma16(pack8(px0 + kt * 32), B[kt], acc0);
                acc1 = mfma16(pack8(px1 + kt * 32), B[kt], acc1);
            }
        }
        if (t > 0) {
            wait32(flags0 + (size_t)(t - 1) * 32, budget);
            const uint16_t* ph0 = ring0 + ((size_t)(t - 1) * NB + nloc) * HID + quad * 8;
#pragma unroll
            for (int kt = 0; kt < 16; ++kt) {
                s16x8 a0 = *(const s16x8*)(ph0 + kt * 32);
                s16x8 a1 = *(const s16x8*)(ph0 + 16 * HID + kt * 32);
                acc0 = mfma16(a0, B[8 + kt], acc0);
                acc1 = mfma16(a1, B[8 + kt], acc1);
            }
        }
#pragma unroll
        for (int r = 0; r < 4; ++r) {
            sh.gbuf[wave][quad * 4 + r][nloc]      = acc0[r];
            sh.gbuf[wave][16 + quad * 4 + r][nloc] = acc1[r];
        }
        __syncthreads();
        {
            const int b = tid >> 3, n = (tid & 7) * 2;
            float2 h = gates2(sh, b, n);
            st_u32(ring0w + ((size_t)t * NB + b) * (HID / 2) + (col0 + n) / 2,
                   pack2bf(h.x, h.y));
        }
        __syncthreads();              // all waves' sc1 stores drained (vmcnt 0)
        if (tid == 0) st_u32(&flags0[(size_t)t * 32 + w], 1u);
    }
}

template<bool R1>
__device__ void body_l1(const float* __restrict__ Wf, const float* __restrict__ Wi,
                        const float* __restrict__ Wc, const float* __restrict__ Wo,
                        const float* __restrict__ bf_, const float* __restrict__ bi_,
                        const float* __restrict__ bc_, const float* __restrict__ bo_,
                        float* __restrict__ out,
                        uint16_t* __restrict__ ring0, uint16_t* __restrict__ ring1,
                        unsigned* __restrict__ flags0, unsigned* __restrict__ flags1,
                        int w)
{
    const int tid  = threadIdx.x;
    const int wave = tid >> 6;
    const int lane = tid & 63;
    const int nloc = lane & 15;
    const int quad = lane >> 4;
    const int col0 = w * 16;
    int budget = SPIN_BUDGET;

    __shared__ Shared sh;
    load_bias_c(sh, bf_, bi_, bc_, bo_, col0);

    const float* Wg = (wave == 0) ? Wf : (wave == 1) ? Wi : (wave == 2) ? Wc : Wo;
    const float* wrow = Wg + (size_t)(col0 + nloc) * 1024 + quad * 8;
    s16x8 B[32];
#pragma unroll
    for (int kt = 0; kt < 32; ++kt) B[kt] = pack8(wrow + kt * 32);

    uint32_t* ring1w = (uint32_t*)ring1;
    __syncthreads();

#pragma unroll 1
    for (int t = 0; t < SEQ; ++t) {
        f32x4 acc0 = {0.f, 0.f, 0.f, 0.f};
        f32x4 acc1 = {0.f, 0.f, 0.f, 0.f};
        // Own-chain recurrence first: h1(t-1) is the critical dependency.
        if (t > 0) {
            wait32(flags1 + (size_t)(t - 1) * 32, budget);
            if (R1) {
                const uint16_t* ph1 = ring1 + ((size_t)(t - 1) * NB + nloc) * HID + quad * 8;
#pragma unroll
                for (int kt = 0; kt < 16; ++kt) {
                    s16x8 a0 = *(const s16x8*)(ph1 + kt * 32);
                    s16x8 a1 = *(const s16x8*)(ph1 + 16 * HID + kt * 32);
                    acc0 = mfma16(a0, B[16 + kt], acc0);
                    acc1 = mfma16(a1, B[16 + kt], acc1);
                }
            } else {
                const float* po0 = out + ((size_t)nloc * SEQ + (t - 1)) * HID + quad * 8;
                const float* po1 = po0 + (size_t)16 * SEQ * HID;
#pragma unroll
                for (int kt = 0; kt < 16; ++kt) {
                    acc0 = mfma16(pack8(po0 + kt * 32), B[16 + kt], acc0);
                    acc1 = mfma16(pack8(po1 + kt * 32), B[16 + kt], acc1);
                }
            }
        }
        // h0(t): L0 runs ahead, so this flag is normally already set.
        wait32(flags0 + (size_t)t * 32, budget);
        {
            const uint16_t* ph0 = ring0 + ((size_t)t * NB + nloc) * HID + quad * 8;
#pragma unroll
            for (int kt = 0; kt < 16; ++kt) {
                s16x8 a0 = *(const s16x8*)(ph0 + kt * 32);
                s16x8 a1 = *(const s16x8*)(ph0 + 16 * HID + kt * 32);
                acc0 = mfma16(a0, B[kt], acc0);
                acc1 = mfma16(a1, B[kt], acc1);
            }
        }
#pragma unroll
        for (int r = 0; r < 4; ++r) {
            sh.gbuf[wave][quad * 4 + r][nloc]      = acc0[r];
            sh.gbuf[wave][16 + quad * 4 + r][nloc] = acc1[r];
        }
        __syncthreads();
        {
            const int b = tid >> 3, n = (tid & 7) * 2;
            float2 h = gates2(sh, b, n);
            float* po = &out[((size_t)b * SEQ + t) * HID + col0 + n];
            if (R1) {
                *(float2*)po = h;    // harness-only; flushed by end-of-kernel L2 writeback
                st_u32(ring1w + ((size_t)t * NB + b) * (HID / 2) + (col0 + n) / 2,
                       pack2bf(h.x, h.y));
            } else {
                uint64_t v = (uint64_t)__float_as_uint(h.x)
                           | ((uint64_t)__float_as_uint(h.y) << 32);
                st_u64((uint64_t*)po, v);   // coherent: consumed by L1 next step
            }
        }
        __syncthreads();
        if (tid == 0) st_u32(&flags1[(size_t)t * 32 + w], 1u);
    }
}

template<bool R1>
__global__ __launch_bounds__(256, 1) void lstm_k(
    const float* __restrict__ x,
    const float* W0f, const float* b0f, const float* W0i, const float* b0i,
    const float* W0c, const float* b0c, const float* W0o, const float* b0o,
    const float* W1f, const float* b1f, const float* W1i, const float* b1i,
    const float* W1c, const float* b1c, const float* W1o, const float* b1o,
    float* out, uint16_t* ring0, uint16_t* ring1,
    unsigned* flags0, unsigned* flags1)
{
    if (blockIdx.x < L0WGS)
        body_l0(x, W0f, W0i, W0c, W0o, b0f, b0i, b0c, b0o,
                ring0, flags0, blockIdx.x);
    else
        body_l1<R1>(W1f, W1i, W1c, W1o, b1f, b1i, b1c, b1o,
                    out, ring0, ring1, flags0, flags1, blockIdx.x - L0WGS);
}

extern "C" void kernel_launch(void* const* d_in, const int* in_sizes, int n_in,
                              void* d_out, int out_size, void* d_ws, size_t ws_size,
                              hipStream_t stream) {
    const float* x   = (const float*)d_in[0];
    const float* W0f = (const float*)d_in[1];  const float* b0f = (const float*)d_in[2];
    const float* W0i = (const float*)d_in[3];  const float* b0i = (const float*)d_in[4];
    const float* W0c = (const float*)d_in[5];  const float* b0c = (const float*)d_in[6];
    const float* W0o = (const float*)d_in[7];  const float* b0o = (const float*)d_in[8];
    const float* W1f = (const float*)d_in[9];  const float* b1f = (const float*)d_in[10];
    const float* W1i = (const float*)d_in[11]; const float* b1i = (const float*)d_in[12];
    const float* W1c = (const float*)d_in[13]; const float* b1c = (const float*)d_in[14];
    const float* W1o = (const float*)d_in[15]; const float* b1o = (const float*)d_in[16];
    float* out = (float*)d_out;

    const size_t flag_bytes = (size_t)SEQ * 32 * 4;          // 128 KiB each
    const size_t ring_bytes = (size_t)SEQ * NB * HID * 2;    // 32 MiB each
    unsigned* flags0 = (unsigned*)d_ws;
    unsigned* flags1 = flags0 + SEQ * 32;
    uint16_t* ring0  = (uint16_t*)((char*)d_ws + 2 * flag_bytes);
    uint16_t* ring1  = (uint16_t*)((char*)d_ws + 2 * flag_bytes + ring_bytes);
    const bool use_r1 = ws_size >= 2 * flag_bytes + 2 * ring_bytes;

    hipMemsetAsync(d_ws, 0, 2 * flag_bytes, stream);   // zero all flags

    if (use_r1)
        hipLaunchKernelGGL(lstm_k<true>, dim3(NWG), dim3(256), 0, stream,
            x, W0f, b0f, W0i, b0i, W0c, b0c, W0o, b0o,
            W1f, b1f, W1i, b1i, W1c, b1c, W1o, b1o,
            out, ring0, ring1, flags0, flags1);
    else
        hipLaunchKernelGGL(lstm_k<false>, dim3(NWG), dim3(256), 0, stream,
            x, W0f, b0f, W0i, b0i, W0c, b0c, W0o, b0o,
            W1f, b1f, W1i, b1i, W1c, b1c, W1o, b1o,
            out, ring0, ring1, flags0, flags1);
}